// Round 14
// baseline (280.495 us; speedup 1.0000x reference)
//
#include <hip/hip_runtime.h>

#define TT   512
#define HH   50
#define MB   8            // batch rows per block
#define NW   13           // waves per block
#define NTHR (NW * 64)    // 832 threads
#define BUFH 2560         // f16 per parity buffer: 5 strips x 512

typedef _Float16 f16x8 __attribute__((ext_vector_type(8)));
typedef float    f32x4 __attribute__((ext_vector_type(4)));

#define L2E 1.4426950408889634f

__device__ __forceinline__ float rcp_f(float v) { return __builtin_amdgcn_rcpf(v); }
__device__ __forceinline__ float ex2_f(float v) { return __builtin_amdgcn_exp2f(v); }

// R10 structure (241 us) + EXEC-MASKED ZERO-SKIP READS.
// 13 waves, grid 256. Wave w owns gate-tile w. Lane (q=l>>4, n=l&15):
// acc[e] = gate e of unit u=4w+q, col n. B operand K=160 block-diagonal:
// rows 0-49 h0 (cols 0-7), rows 50-99 h0copy (cols 8-15), rows 100-149 h1
// (cols 8-15), rest zeros. A = [W_hh0|W_ih1|W_hh1|0] stacked along K,
// pre-scaled by -log2e (i,f,o) / +2log2e (g); bias + x*W_ih0 in MFMA C.
// NEW vs R10: lanes whose 16B B-fragment is structurally all-zero SKIP the
// ds_read entirely (fragment pre-zeroed in VGPRs; read under divergent if ->
// exec-masked ds_read, inactive lanes issue no LDS requests). 160 of 320
// lane-reads vanish; remaining lanes keep the linear conflict-free pattern.
// One barrier per step; layer 1 pipelined one step behind layer 0.
__global__ __launch_bounds__(NTHR, 1)
void lstm2_kernel(const float* __restrict__ x,
                  const float* __restrict__ W_ih0, const float* __restrict__ W_hh0,
                  const float* __restrict__ b_ih0, const float* __restrict__ b_hh0,
                  const float* __restrict__ W_ih1, const float* __restrict__ W_hh1,
                  const float* __restrict__ b_ih1, const float* __restrict__ b_hh1,
                  const float* __restrict__ W_fc,  const float* __restrict__ b_fc,
                  float* __restrict__ out)
{
    // B layout per parity buf: f16 offset(row r, col c) =
    //   (r>>5)*512 + ((r>>3)&3)*128 + c*8 + (r&7)
    // Lane l's strip-ki read = buf + ki*512 + 8*l (16B, lane-linear, conflict-free).
    __shared__ __align__(16) _Float16 shh[2][BUFH];          // 10 KiB
    __shared__ float sh_x[MB][TT + 4];
    __shared__ float shf[MB][52];
    __shared__ float sh_wfc[HH];

    const int tid = threadIdx.x;
    const int w   = tid >> 6;
    const int l   = tid & 63;
    const int q   = l >> 4;
    const int n   = l & 15;
    const int b0  = blockIdx.x * MB;

    for (int i = tid; i < 2 * BUFH; i += NTHR) (&shh[0][0])[i] = (_Float16)0.0f;
    for (int i = tid; i < MB * TT; i += NTHR)
        sh_x[i >> 9][i & (TT - 1)] = x[(size_t)b0 * TT + i];
    for (int i = tid; i < HH; i += NTHR) sh_wfc[i] = W_fc[i];

    // ---- A fragments: K=160 concat [W_hh0 | W_ih1 | W_hh1 | 0], pre-scaled.
    // A-row r=n -> unit 4w+(n>>2), gate n&3, weight row grow = (n&3)*HH + u_r.
    // k-map: k = ki*32 + q*8 + e (same bijection as B layout -> sums correct).
    const int  u_r   = w * 4 + (n >> 2);
    const bool rowok = (u_r < HH);
    const int  grow  = (n & 3) * HH + (rowok ? u_r : 0);
    const float srow = ((n & 3) == 2) ? (2.0f * L2E) : (-L2E);

    f16x8 wf[5];
    #pragma unroll
    for (int ki = 0; ki < 5; ++ki) {
        #pragma unroll
        for (int e = 0; e < 8; ++e) {
            int k = ki * 32 + q * 8 + e;
            float v = 0.0f;
            if (rowok) {
                if      (k < HH)           v = W_hh0[grow * HH + k];
                else if (k < 2 * HH)       v = W_ih1[grow * HH + (k - HH)];
                else if (k < 3 * HH)       v = W_hh1[grow * HH + (k - 2 * HH)];
            }
            wf[ki][e] = (_Float16)(srow * v);
        }
    }

    // ---- chain identity: lane n<8 = L0 batch n; n>=8 = L1 batch n-8 ----
    const bool isL1 = (n >= 8);
    const int  u    = 4 * w + q;
    const int  cb   = n & 7;
    const bool wr   = (u < HH);
    const int  uc   = wr ? u : 0;

    float bz[4], wz[4];
    #pragma unroll
    for (int e = 0; e < 4; ++e) {
        int gr = e * HH + uc;
        float sc = (e == 2) ? (2.0f * L2E) : (-L2E);
        bz[e] = sc * (isL1 ? (b_ih1[gr] + b_hh1[gr]) : (b_ih0[gr] + b_hh0[gr]));
        wz[e] = isL1 ? 0.0f : (sc * W_ih0[gr]);
    }

    // ---- read predicates (per-strip structural-nonzero masks, audited):
    //  b0: lo            b1: lo ? q<3 : q>=2    b2,b3: hi    b4: hi && q<3
    const bool lo = (n < 8);
    const bool hi = !lo;
    const bool m1 = lo ? (q < 3) : (q >= 2);
    const bool m4 = hi && (q < 3);

    const _Float16* rb = &shh[0][8 * l];               // + P*BUFH + ki*512

    // write offsets (same as R10)
    auto offrc = [](int r, int c) {
        return (r >> 5) * 512 + ((r >> 3) & 3) * 128 + c * 8 + (r & 7);
    };
    const int oa = isL1 ? offrc(100 + uc, cb + 8) : offrc(uc, cb);
    const int ob = offrc(50 + uc, cb + 8);
    _Float16* wpa0 = &shh[1][oa];   // step P=0 writes buf 1
    _Float16* wpa1 = &shh[0][oa];
    _Float16* wpb0 = &shh[1][ob];
    _Float16* wpb1 = &shh[0][ob];

    const float* xq = &sh_x[cb][0];
    float cst = 0.0f;

    __syncthreads();

#define MFMA(A, B, C) __builtin_amdgcn_mfma_f32_16x16x32_f16((A), (B), (C), 0, 0, 0)

#define STEP(P, T0, XI)                                                           \
    {                                                                             \
        float xi = (XI);                                                          \
        f32x4 cin;                                                                \
        cin[0] = __builtin_fmaf(xi, wz[0], bz[0]);                                \
        cin[1] = __builtin_fmaf(xi, wz[1], bz[1]);                                \
        cin[2] = __builtin_fmaf(xi, wz[2], bz[2]);                                \
        cin[3] = __builtin_fmaf(xi, wz[3], bz[3]);                                \
        const _Float16* base = rb + (P) * BUFH;                                   \
        f16x8 zf = {(_Float16)0, (_Float16)0, (_Float16)0, (_Float16)0,           \
                    (_Float16)0, (_Float16)0, (_Float16)0, (_Float16)0};          \
        f16x8 b0 = zf, b1 = zf, b2 = zf, b3 = zf, b4 = zf;                        \
        if (lo) b0 = *(const f16x8*)(base);                                       \
        if (m1) b1 = *(const f16x8*)(base + 512);                                 \
        if (hi) {                                                                 \
            b2 = *(const f16x8*)(base + 1024);                                    \
            b3 = *(const f16x8*)(base + 1536);                                    \
        }                                                                         \
        if (m4) b4 = *(const f16x8*)(base + 2048);                                \
        f32x4 a = MFMA(wf[0], b0, cin);                                           \
        a = MFMA(wf[1], b1, a);                                                   \
        a = MFMA(wf[2], b2, a);                                                   \
        a = MFMA(wf[3], b3, a);                                                   \
        a = MFMA(wf[4], b4, a);                                                   \
        float eI = ex2_f(a[0]), eF = ex2_f(a[1]), tG = ex2_f(a[2]), eO = ex2_f(a[3]); \
        float dI = 1.0f + eI, dF = 1.0f + eF, dO = 1.0f + eO;                     \
        float IG = (tG - 1.0f) * rcp_f(dI * (tG + 1.0f));                         \
        float cn = __builtin_fmaf(rcp_f(dF), cst, IG);                            \
        cst = ((T0) && isL1) ? 0.0f : cn;                                         \
        float cc = __builtin_amdgcn_fmed3f(cst, -16.0f, 16.0f);                   \
        float tc = ex2_f(cc * (2.0f * L2E));                                      \
        float hv = (tc - 1.0f) * rcp_f(dO * (tc + 1.0f));                         \
        if (wr && !((T0) && isL1)) {                                              \
            _Float16 h16 = (_Float16)hv;                                          \
            *((P) ? wpa1 : wpa0) = h16;                                           \
            if (!isL1) *((P) ? wpb1 : wpb0) = h16;                                \
        }                                                                         \
        __syncthreads();                                                          \
    }

    // t=0 (P=0): L1 chain suppressed (h1(-1) stays 0)
    STEP(0, 1, xq[0])
    // t=1..510: 255 (odd,even) pairs
    for (int k2 = 0; k2 < 255; ++k2) {
        STEP(1, 0, xq[1])
        STEP(0, 0, xq[2])
        xq += 2;
    }
    // t=511 (P=1): writes h0(511), h1(510) into buf 0
    STEP(1, 0, xq[1])
#undef STEP

    // ---- tail: h1(511) from buf 0 (h0(511) rows 0-99, h1(510) rows 100-149) ----
    {
        f32x4 cin = {bz[0], bz[1], bz[2], bz[3]};
        f16x8 zf = {(_Float16)0, (_Float16)0, (_Float16)0, (_Float16)0,
                    (_Float16)0, (_Float16)0, (_Float16)0, (_Float16)0};
        f16x8 b0 = zf, b1 = zf, b2 = zf, b3 = zf, b4 = zf;
        if (lo) b0 = *(const f16x8*)(rb);
        if (m1) b1 = *(const f16x8*)(rb + 512);
        if (hi) {
            b2 = *(const f16x8*)(rb + 1024);
            b3 = *(const f16x8*)(rb + 1536);
        }
        if (m4) b4 = *(const f16x8*)(rb + 2048);
        f32x4 a = MFMA(wf[0], b0, cin);
        a = MFMA(wf[1], b1, a);
        a = MFMA(wf[2], b2, a);
        a = MFMA(wf[3], b3, a);
        a = MFMA(wf[4], b4, a);
        if (isL1 && wr) {
            float eI = ex2_f(a[0]), eF = ex2_f(a[1]), tG = ex2_f(a[2]), eO = ex2_f(a[3]);
            float dI = 1.0f + eI, dF = 1.0f + eF, dO = 1.0f + eO;
            float IG = (tG - 1.0f) * rcp_f(dI * (tG + 1.0f));
            float cn = __builtin_fmaf(rcp_f(dF), cst, IG);
            float cc = __builtin_amdgcn_fmed3f(cn, -16.0f, 16.0f);
            float tc = ex2_f(cc * (2.0f * L2E));
            shf[cb][uc] = (tc - 1.0f) * rcp_f(dO * (tc + 1.0f));
        }
    }
    __syncthreads();

    if (tid < MB) {
        float s = b_fc[0];
        for (int j = 0; j < HH; ++j) s += shf[tid][j] * sh_wfc[j];
        out[b0 + tid] = s;
    }
#undef MFMA
}

extern "C" void kernel_launch(void* const* d_in, const int* in_sizes, int n_in,
                              void* d_out, int out_size, void* d_ws, size_t ws_size,
                              hipStream_t stream) {
    const float* xin   = (const float*)d_in[0];
    const float* W_ih0 = (const float*)d_in[1];
    const float* W_hh0 = (const float*)d_in[2];
    const float* b_ih0 = (const float*)d_in[3];
    const float* b_hh0 = (const float*)d_in[4];
    const float* W_ih1 = (const float*)d_in[5];
    const float* W_hh1 = (const float*)d_in[6];
    const float* b_ih1 = (const float*)d_in[7];
    const float* b_hh1 = (const float*)d_in[8];
    const float* W_fc  = (const float*)d_in[9];
    const float* b_fc  = (const float*)d_in[10];
    float* out = (float*)d_out;

    lstm2_kernel<<<dim3(2048 / MB), dim3(NTHR), 0, stream>>>(
        xin, W_ih0, W_hh0, b_ih0, b_hh0, W_ih1, W_hh1, b_ih1, b_hh1, W_fc, b_fc, out);
}

// Round 16
// 240.252 us; speedup vs baseline: 1.1675x; 1.1675x over previous
//
#include <hip/hip_runtime.h>

#define TT   512
#define HH   50
#define MB   8            // batch rows per block
#define NW   13           // waves per block
#define NTHR (NW * 64)    // 832 threads
#define BUFH 2560         // f16 per parity buffer: 5 strips x 512

typedef _Float16 f16x8 __attribute__((ext_vector_type(8)));
typedef float    f32x4 __attribute__((ext_vector_type(4)));

#define L2E 1.4426950408889634f

__device__ __forceinline__ float rcp_f(float v) { return __builtin_amdgcn_rcpf(v); }
__device__ __forceinline__ float ex2_f(float v) { return __builtin_amdgcn_exp2f(v); }

// R10 configuration (best verified: 241 us, absmax 4.88e-4).
// 13 waves, grid 256. Wave w owns gate-tile w (units 4w..4w+3, A-rows interleaved
// i,f,g,o). Lane (q=l>>4, n=l&15): acc[e] = gate e of unit u=4w+q, col n.
// EXTENDED-K: B operand is K=160 rows = [h0 (cols 0-7) | h0copy (cols 8-15) |
// h1 (cols 8-15) | zeros]; A = [W_hh0 | W_ih1 | W_hh1 | 0] stacked along K,
// pre-scaled by -log2e (i,f,o) / +2log2e (g). One 5-MFMA chain gives every
// lane its own chain's gates directly (no selects, no acc merges).
// Bias + x*W_ih0 ride in the MFMA C operand (cin), computed pre-MFMA.
// Lanes n<8 run L0 chains, n>=8 run L1. One barrier per step; layer 1 pipelined
// one step behind layer 0.
__global__ __launch_bounds__(NTHR, 1)
void lstm2_kernel(const float* __restrict__ x,
                  const float* __restrict__ W_ih0, const float* __restrict__ W_hh0,
                  const float* __restrict__ b_ih0, const float* __restrict__ b_hh0,
                  const float* __restrict__ W_ih1, const float* __restrict__ W_hh1,
                  const float* __restrict__ b_ih1, const float* __restrict__ b_hh1,
                  const float* __restrict__ W_fc,  const float* __restrict__ b_fc,
                  float* __restrict__ out)
{
    // B layout per parity buf: f16 offset(row r, col c) =
    //   (r>>5)*512 + ((r>>3)&3)*128 + c*8 + (r&7)
    // Lane l's strip-ki read = buf + ki*512 + 8*l (16B, lane-linear, conflict-free).
    __shared__ __align__(16) _Float16 shh[2][BUFH];          // 10 KiB
    __shared__ float sh_x[MB][TT + 4];
    __shared__ float shf[MB][52];
    __shared__ float sh_wfc[HH];

    const int tid = threadIdx.x;
    const int w   = tid >> 6;
    const int l   = tid & 63;
    const int q   = l >> 4;
    const int n   = l & 15;
    const int b0  = blockIdx.x * MB;

    for (int i = tid; i < 2 * BUFH; i += NTHR) (&shh[0][0])[i] = (_Float16)0.0f;
    for (int i = tid; i < MB * TT; i += NTHR)
        sh_x[i >> 9][i & (TT - 1)] = x[(size_t)b0 * TT + i];
    for (int i = tid; i < HH; i += NTHR) sh_wfc[i] = W_fc[i];

    // ---- A fragments: K=160 concat [W_hh0 | W_ih1 | W_hh1 | 0], pre-scaled.
    // A-row r=n -> unit 4w+(n>>2), gate n&3, weight row grow = (n&3)*HH + u_r.
    // k-map: k = ki*32 + q*8 + e (same bijection as B layout -> sums correct).
    const int  u_r   = w * 4 + (n >> 2);
    const bool rowok = (u_r < HH);
    const int  grow  = (n & 3) * HH + (rowok ? u_r : 0);
    const float srow = ((n & 3) == 2) ? (2.0f * L2E) : (-L2E);

    f16x8 wf[5];
    #pragma unroll
    for (int ki = 0; ki < 5; ++ki) {
        #pragma unroll
        for (int e = 0; e < 8; ++e) {
            int k = ki * 32 + q * 8 + e;
            float v = 0.0f;
            if (rowok) {
                if      (k < HH)           v = W_hh0[grow * HH + k];
                else if (k < 2 * HH)       v = W_ih1[grow * HH + (k - HH)];
                else if (k < 3 * HH)       v = W_hh1[grow * HH + (k - 2 * HH)];
            }
            wf[ki][e] = (_Float16)(srow * v);
        }
    }

    // ---- chain identity: lane n<8 = L0 batch n; n>=8 = L1 batch n-8 ----
    const bool isL1 = (n >= 8);
    const int  u    = 4 * w + q;
    const int  cb   = n & 7;
    const bool wr   = (u < HH);
    const int  uc   = wr ? u : 0;

    float bz[4], wz[4];
    #pragma unroll
    for (int e = 0; e < 4; ++e) {
        int gr = e * HH + uc;
        float sc = (e == 2) ? (2.0f * L2E) : (-L2E);
        bz[e] = sc * (isL1 ? (b_ih1[gr] + b_hh1[gr]) : (b_ih0[gr] + b_hh0[gr]));
        wz[e] = isL1 ? 0.0f : (sc * W_ih0[gr]);
    }

    // ---- LDS pointers ----
    auto offrc = [](int r, int c) {
        return (r >> 5) * 512 + ((r >> 3) & 3) * 128 + c * 8 + (r & 7);
    };
    const _Float16* rb = &shh[0][8 * l];               // + P*BUFH + ki*512
    // primary write: L0 -> row uc col cb; L1 -> row 100+uc col cb+8
    const int oa = isL1 ? offrc(100 + uc, cb + 8) : offrc(uc, cb);
    // copy write (L0 only): row 50+uc col cb+8
    const int ob = offrc(50 + uc, cb + 8);
    _Float16* wpa0 = &shh[1][oa];   // step P=0 writes buf 1
    _Float16* wpa1 = &shh[0][oa];
    _Float16* wpb0 = &shh[1][ob];
    _Float16* wpb1 = &shh[0][ob];

    const float* xq = &sh_x[cb][0];
    float cst = 0.0f;

    __syncthreads();

#define MFMA(A, B, C) __builtin_amdgcn_mfma_f32_16x16x32_f16((A), (B), (C), 0, 0, 0)

#define STEP(P, T0, XI)                                                           \
    {                                                                             \
        float xi = (XI);                                                          \
        f32x4 cin;                                                                \
        cin[0] = __builtin_fmaf(xi, wz[0], bz[0]);                                \
        cin[1] = __builtin_fmaf(xi, wz[1], bz[1]);                                \
        cin[2] = __builtin_fmaf(xi, wz[2], bz[2]);                                \
        cin[3] = __builtin_fmaf(xi, wz[3], bz[3]);                                \
        f16x8 b0 = *(const f16x8*)(rb + (P) * BUFH);                              \
        f16x8 b1 = *(const f16x8*)(rb + (P) * BUFH + 512);                        \
        f16x8 b2 = *(const f16x8*)(rb + (P) * BUFH + 1024);                       \
        f16x8 b3 = *(const f16x8*)(rb + (P) * BUFH + 1536);                       \
        f16x8 b4 = *(const f16x8*)(rb + (P) * BUFH + 2048);                       \
        f32x4 a = MFMA(wf[0], b0, cin);                                           \
        a = MFMA(wf[1], b1, a);                                                   \
        a = MFMA(wf[2], b2, a);                                                   \
        a = MFMA(wf[3], b3, a);                                                   \
        a = MFMA(wf[4], b4, a);                                                   \
        float eI = ex2_f(a[0]), eF = ex2_f(a[1]), tG = ex2_f(a[2]), eO = ex2_f(a[3]); \
        float dI = 1.0f + eI, dF = 1.0f + eF, dO = 1.0f + eO;                     \
        float IG = (tG - 1.0f) * rcp_f(dI * (tG + 1.0f));                         \
        float cn = __builtin_fmaf(rcp_f(dF), cst, IG);                            \
        cst = ((T0) && isL1) ? 0.0f : cn;                                         \
        float cc = __builtin_amdgcn_fmed3f(cst, -16.0f, 16.0f);                   \
        float tc = ex2_f(cc * (2.0f * L2E));                                      \
        float hv = (tc - 1.0f) * rcp_f(dO * (tc + 1.0f));                         \
        if (wr && !((T0) && isL1)) {                                              \
            _Float16 h16 = (_Float16)hv;                                          \
            *((P) ? wpa1 : wpa0) = h16;                                           \
            if (!isL1) *((P) ? wpb1 : wpb0) = h16;                                \
        }                                                                         \
        __syncthreads();                                                          \
    }

    // t=0 (P=0): L1 chain suppressed (h1(-1) stays 0)
    STEP(0, 1, xq[0])
    // t=1..510: 255 (odd,even) pairs
    for (int k2 = 0; k2 < 255; ++k2) {
        STEP(1, 0, xq[1])
        STEP(0, 0, xq[2])
        xq += 2;
    }
    // t=511 (P=1): writes h0(511), h1(510) into buf 0
    STEP(1, 0, xq[1])
#undef STEP

    // ---- tail: h1(511) from buf 0 (h0(511) rows 0-99, h1(510) rows 100-149) ----
    {
        f32x4 cin = {bz[0], bz[1], bz[2], bz[3]};
        f16x8 b0 = *(const f16x8*)(rb);
        f16x8 b1 = *(const f16x8*)(rb + 512);
        f16x8 b2 = *(const f16x8*)(rb + 1024);
        f16x8 b3 = *(const f16x8*)(rb + 1536);
        f16x8 b4 = *(const f16x8*)(rb + 2048);
        f32x4 a = MFMA(wf[0], b0, cin);
        a = MFMA(wf[1], b1, a);
        a = MFMA(wf[2], b2, a);
        a = MFMA(wf[3], b3, a);
        a = MFMA(wf[4], b4, a);
        if (isL1 && wr) {
            float eI = ex2_f(a[0]), eF = ex2_f(a[1]), tG = ex2_f(a[2]), eO = ex2_f(a[3]);
            float dI = 1.0f + eI, dF = 1.0f + eF, dO = 1.0f + eO;
            float IG = (tG - 1.0f) * rcp_f(dI * (tG + 1.0f));
            float cn = __builtin_fmaf(rcp_f(dF), cst, IG);
            float cc = __builtin_amdgcn_fmed3f(cn, -16.0f, 16.0f);
            float tc = ex2_f(cc * (2.0f * L2E));
            shf[cb][uc] = (tc - 1.0f) * rcp_f(dO * (tc + 1.0f));
        }
    }
    __syncthreads();

    if (tid < MB) {
        float s = b_fc[0];
        for (int j = 0; j < HH; ++j) s += shf[tid][j] * sh_wfc[j];
        out[b0 + tid] = s;
    }
#undef MFMA
}

extern "C" void kernel_launch(void* const* d_in, const int* in_sizes, int n_in,
                              void* d_out, int out_size, void* d_ws, size_t ws_size,
                              hipStream_t stream) {
    const float* xin   = (const float*)d_in[0];
    const float* W_ih0 = (const float*)d_in[1];
    const float* W_hh0 = (const float*)d_in[2];
    const float* b_ih0 = (const float*)d_in[3];
    const float* b_hh0 = (const float*)d_in[4];
    const float* W_ih1 = (const float*)d_in[5];
    const float* W_hh1 = (const float*)d_in[6];
    const float* b_ih1 = (const float*)d_in[7];
    const float* b_hh1 = (const float*)d_in[8];
    const float* W_fc  = (const float*)d_in[9];
    const float* b_fc  = (const float*)d_in[10];
    float* out = (float*)d_out;

    lstm2_kernel<<<dim3(2048 / MB), dim3(NTHR), 0, stream>>>(
        xin, W_ih0, W_hh0, b_ih0, b_hh0, W_ih1, W_hh1, b_ih1, b_hh1, W_fc, b_fc, out);
}